// Round 3
// baseline (684.281 us; speedup 1.0000x reference)
//
#include <hip/hip_runtime.h>
#include <cstdint>
#include <cstddef>

typedef __attribute__((ext_vector_type(8))) short bhalf8;   // 8 bf16 in 4 VGPRs
typedef __attribute__((ext_vector_type(4))) float f32x4;

__device__ __forceinline__ unsigned short f2bf(float f){
    unsigned int u = __float_as_uint(f);
    u += 0x7fffu + ((u >> 16) & 1u);          // round-to-nearest-even
    return (unsigned short)(u >> 16);
}

// gelu(x) = 0.5x(1+tanh(c0(x+0.044715x^3))) = x - x/(e+1), e = exp(2*c0*(...))
__device__ __forceinline__ float gelu_tanh(float x){
    const float c1 = 2.302584f;                // 2*log2(e)*sqrt(2/pi)
    float y  = x + 0.044715f * x * x * x;
    float e  = __builtin_amdgcn_exp2f(c1 * y); // e^(2*c0*y); inf/0 at extremes ok
    float r  = __builtin_amdgcn_rcpf(e + 1.0f);
    return x - x * r;                          // e=inf -> x; e=0 -> 0
}

// async global->LDS, 16B per lane; LDS dest must be wave-uniform base + lane*16.
__device__ __forceinline__ void async_lds16(const unsigned short* g, unsigned short* l){
    __builtin_amdgcn_global_load_lds(
        (const __attribute__((address_space(1))) void*)g,
        (__attribute__((address_space(3))) void*)l, 16, 0, 0);
}

// ---------------------------------------------------------------------------
// Fused: blocks 0-1 run top-k(32)+softmax (1 wave); blocks 2..2049 convert
// x fp32 -> bf16 (independent of the topk results).
// ---------------------------------------------------------------------------
__global__ void topk_conv_kernel(const float* __restrict__ lg1,
                                 const float* __restrict__ lg2,
                                 int* __restrict__ idx_out,
                                 float* __restrict__ w_out,
                                 const float* __restrict__ x,
                                 unsigned short* __restrict__ x16)
{
    __shared__ float svals[32];
    const int b = blockIdx.x;
    if (b >= 2){                        // ---- x -> bf16
        int v = (b - 2) * 256 + threadIdx.x;
        float4 xx = ((const float4*)x)[v];
        ushort4 o; o.x=f2bf(xx.x); o.y=f2bf(xx.y); o.z=f2bf(xx.z); o.w=f2bf(xx.w);
        ((ushort4*)x16)[v] = o;
        return;
    }
    if (threadIdx.x >= 64) return;      // topk uses a single wave
    const float* lg = (b == 0) ? lg1 : lg2;
    int*   idxo = idx_out + b * 32;
    float* wo   = w_out   + b * 32;
    const int lane = threadIdx.x;       // 0..63
    float v[4];
    #pragma unroll
    for (int j = 0; j < 4; ++j) v[j] = lg[lane * 4 + j];
    for (int k = 0; k < 32; ++k){
        float bv = -1e30f; int bi = 0;
        #pragma unroll
        for (int j = 0; j < 4; ++j){
            if (v[j] > bv){ bv = v[j]; bi = lane * 4 + j; }
        }
        for (int off = 32; off > 0; off >>= 1){
            float ov = __shfl_down(bv, off);
            int   oi = __shfl_down(bi, off);
            if (ov > bv){ bv = ov; bi = oi; }
        }
        bi = __shfl(bi, 0);
        if (lane == 0){ svals[k] = bv; idxo[k] = bi; }   // svals descending
        if ((bi >> 2) == lane) v[bi & 3] = -1e30f;
    }
    // parallel softmax: svals[0] is the max (selection order is descending)
    float sv = svals[lane & 31];
    float e  = expf(sv - svals[0]);
    float s  = e;
    #pragma unroll
    for (int off = 16; off > 0; off >>= 1) s += __shfl_xor(s, off);
    if (lane < 32) wo[lane] = e / s;
}

// ---------------------------------------------------------------------------
// All four gathers in ONE launch (block-range dispatch):
//   [0,2048)      : nat gather fc1_A -> Ag1  (scaled)
//   [2048,10240)  : nat gather fc2_A -> Ag2
//   [10240,12288) : tr  gather fc1_B -> Bt1
//   [12288,12800) : tr  gather fc2_B -> Bg2t (scaled)
// Block 0 also zeroes the 128 split-K tile counters for gemm4.
// ---------------------------------------------------------------------------
__global__ void gather_kernel(const float* __restrict__ fc1A, unsigned short* __restrict__ Ag1,
                              const float* __restrict__ fc1B, unsigned short* __restrict__ Bt1,
                              const float* __restrict__ fc2A, unsigned short* __restrict__ Ag2,
                              const float* __restrict__ fc2B, unsigned short* __restrict__ Bg2t,
                              const int* __restrict__ idxb, const float* __restrict__ wb,
                              int* __restrict__ cnt)
{
    __shared__ float tile[64][65];
    const int t = threadIdx.x;
    int b = blockIdx.x;

    if (b == 0 && t < 128) cnt[t] = 0;              // reset gemm4 tile counters

    if (b < 10240){                                 // ---- natural gathers
        const float* src; unsigned short* dst; const int* idx; const float* w;
        int Drows, use_scale, v;
        if (b < 2048){ src=fc1A; dst=Ag1; idx=idxb;    w=wb;    Drows=1024; use_scale=1; v=b*256+t; }
        else         { src=fc2A; dst=Ag2; idx=idxb+32; w=wb+32; Drows=4096; use_scale=0; v=(b-2048)*256+t; }
        int c4 = v & 511;          // 512 float4 per dst row (2048 cols)
        int d  = v >> 9;
        int k  = c4 >> 4;          // expert slot 0..31
        int r4 = c4 & 15;
        int p  = idx[k];
        float sc = use_scale ? w[k] : 1.0f;
        float4 xx = *((const float4*)(src + ((size_t)p * Drows + d) * 64) + r4);
        ushort4 o;
        o.x = f2bf(sc * xx.x); o.y = f2bf(sc * xx.y);
        o.z = f2bf(sc * xx.z); o.w = f2bf(sc * xx.w);
        *(ushort4*)(dst + (size_t)d * 2048 + k * 64 + r4 * 4) = o;
        return;
    }
    b -= 10240;                                     // ---- transpose gathers
    const float* src; unsigned short* dst; const int* idx; const float* w;
    int Fcols, use_scale;
    if (b < 2048){ src=fc1B; dst=Bt1;  idx=idxb;    w=wb;    Fcols=4096; use_scale=0; }
    else         { src=fc2B; dst=Bg2t; idx=idxb+32; w=wb+32; Fcols=1024; use_scale=1; b -= 2048; }
    const int k  = b & 31;
    const int f0 = (b >> 5) * 64;
    const int p  = idx[k];
    const float sc = use_scale ? w[k] : 1.0f;
    const int cf = t & 15;
    const int r0 = t >> 4;
    #pragma unroll
    for (int pass = 0; pass < 4; ++pass){
        int r = r0 + pass * 16;
        float4 xx = *((const float4*)(src + ((size_t)p * 64 + r) * Fcols + f0) + cf);
        tile[r][cf * 4 + 0] = xx.x; tile[r][cf * 4 + 1] = xx.y;
        tile[r][cf * 4 + 2] = xx.z; tile[r][cf * 4 + 3] = xx.w;
    }
    __syncthreads();
    const int r4  = t & 15;
    const int fl0 = t >> 4;
    #pragma unroll
    for (int pass = 0; pass < 4; ++pass){
        int fl = fl0 + pass * 16;
        ushort4 o;
        o.x = f2bf(sc * tile[r4 * 4 + 0][fl]);
        o.y = f2bf(sc * tile[r4 * 4 + 1][fl]);
        o.z = f2bf(sc * tile[r4 * 4 + 2][fl]);
        o.w = f2bf(sc * tile[r4 * 4 + 3][fl]);
        *(ushort4*)(dst + (size_t)(f0 + fl) * 2048 + k * 64 + r4 * 4) = o;
    }
}

// ---------------------------------------------------------------------------
// NT bf16 GEMM body: C(M,N) = A(M,K)*Bt(N,K)^T, fp32 acc, 128x128 tile.
// 2-phase double-buffered pipeline: 2 LDS slots x 32KB, next K-tile's 8
// global_load_lds issued BEFORE current tile's ds_read+MFMA, one drain +
// s_barrier per K-step (loads hide under the 32-MFMA compute phase).
// Per-slot layout (shorts): A0=0 A1=4096 B0=8192 B1=12288, halves at +2048.
// EPI: 0 bf16 store, 1 gelu+bf16 store,
//      4 fp32 split-K partial + last-arriver cross-XCD reduce into outp.
// ---------------------------------------------------------------------------
template<int EPI>
__device__ __forceinline__ void gemm_body(unsigned short* smem,
                                          const unsigned short* __restrict__ A,
                                          const unsigned short* __restrict__ Bt,
                                          void* __restrict__ Cout,
                                          int N, int K, int Kslice, int kbeg,
                                          int bm, int bn,
                                          float* part = nullptr,
                                          float* outp = nullptr,
                                          int* cnt = nullptr,
                                          int tileid = 0)
{
    const int t    = threadIdx.x;
    const int wave = t >> 6;
    const int lane = t & 63;
    const int wr   = (wave >> 1) * 64;
    const int wc   = (wave & 1) * 64;
    const int m16  = lane & 15;
    const int quad = lane >> 4;
    const int srow = t >> 2;             // 64 rows per staging pass
    const int scol = t & 3;              // 16B chunk within 64B (BK=32) row

    f32x4 acc[4][4];
    const f32x4 z = {0.f, 0.f, 0.f, 0.f};
    #pragma unroll
    for (int i = 0; i < 4; ++i)
        #pragma unroll
        for (int j = 0; j < 4; ++j) acc[i][j] = z;

    const unsigned short* Arow = A  + (size_t)(bm + srow) * K + scol * 8 + kbeg;
    const unsigned short* Brow = Bt + (size_t)(bn + srow) * K + scol * 8 + kbeg;
    const size_t rstep = (size_t)64 * K;

    auto stage = [&](int slot, int k0){
        unsigned short* s = smem + slot * 16384 + t * 8;
        async_lds16(Arow + k0,              s);
        async_lds16(Arow + rstep + k0,      s + 2048);
        async_lds16(Arow + k0 + 32,         s + 4096);
        async_lds16(Arow + rstep + k0 + 32, s + 6144);
        async_lds16(Brow + k0,              s + 8192);
        async_lds16(Brow + rstep + k0,      s + 10240);
        async_lds16(Brow + k0 + 32,         s + 12288);
        async_lds16(Brow + rstep + k0 + 32, s + 14336);
    };

    const int nIter = Kslice >> 6;

    // prologue: tile 0 into slot 0
    stage(0, 0);
    asm volatile("s_waitcnt vmcnt(0)" ::: "memory");
    __builtin_amdgcn_s_barrier();

    for (int it = 0; it < nIter; ++it){
        unsigned short* sb = smem + (it & 1) * 16384;
        if (it + 1 < nIter) stage((it + 1) & 1, (it + 1) * 64);  // prefetch

        bhalf8 af0[4], bf0[4], af1[4], bf1[4];
        #pragma unroll
        for (int i = 0; i < 4; ++i){
            af0[i] = *(const bhalf8*)(sb +         (wr + i * 16 + m16) * 32 + quad * 8);
            af1[i] = *(const bhalf8*)(sb + 4096  + (wr + i * 16 + m16) * 32 + quad * 8);
        }
        #pragma unroll
        for (int j = 0; j < 4; ++j){
            bf0[j] = *(const bhalf8*)(sb + 8192  + (wc + j * 16 + m16) * 32 + quad * 8);
            bf1[j] = *(const bhalf8*)(sb + 12288 + (wc + j * 16 + m16) * 32 + quad * 8);
        }

        #pragma unroll
        for (int i = 0; i < 4; ++i)
            #pragma unroll
            for (int j = 0; j < 4; ++j)
                acc[i][j] = __builtin_amdgcn_mfma_f32_16x16x32_bf16(af0[i], bf0[j], acc[i][j], 0, 0, 0);
        #pragma unroll
        for (int i = 0; i < 4; ++i)
            #pragma unroll
            for (int j = 0; j < 4; ++j)
                acc[i][j] = __builtin_amdgcn_mfma_f32_16x16x32_bf16(af1[i], bf1[j], acc[i][j], 0, 0, 0);

        if (it + 1 < nIter){
            asm volatile("s_waitcnt vmcnt(0) lgkmcnt(0)" ::: "memory");
            __builtin_amdgcn_s_barrier();
        }
    }

    // Epilogue. C/D layout: col = lane&15, row = quad*4 + reg  [m89/m91]
    #pragma unroll
    for (int i = 0; i < 4; ++i){
        #pragma unroll
        for (int j = 0; j < 4; ++j){
            #pragma unroll
            for (int r = 0; r < 4; ++r){
                int row = bm + wr + i * 16 + quad * 4 + r;
                int col = bn + wc + j * 16 + m16;
                float vv = acc[i][j][r];
                if (EPI == 1) vv = gelu_tanh(vv);
                if (EPI == 4) ((float*)Cout)[(size_t)row * N + col] = vv;
                else ((unsigned short*)Cout)[(size_t)row * N + col] = f2bf(vv);
            }
        }
    }

    if (EPI == 4){
        // Split-K sync: release own partial, count arrivals at agent scope;
        // 4th arriver reduces all 4 slices into outp (same pairwise order as
        // the old reduce4 kernel -> identical numerics).
        __threadfence();                       // release (wbL2: visible device-wide)
        __syncthreads();
        int* flag = (int*)smem;                // LDS idle after K-loop
        if (t == 0)
            *flag = __hip_atomic_fetch_add(&cnt[tileid], 1,
                                           __ATOMIC_ACQ_REL, __HIP_MEMORY_SCOPE_AGENT);
        __syncthreads();
        if (*flag == 3){
            __threadfence();                   // acquire (invalidate stale L1/L2)
            const float4* p4 = (const float4*)part;
            float4* o4 = (float4*)outp;
            const int S4 = 524288;             // float4 per slice (2048x1024 fp32)
            #pragma unroll
            for (int i2 = 0; i2 < 16; ++i2){
                int pos = i2 * 256 + t;        // 0..4095 within the 128x128 tile
                int g4  = (bm + (pos >> 5)) * 256 + (bn >> 2) + (pos & 31);
                float4 a = p4[g4], b2 = p4[g4 + S4], c2 = p4[g4 + 2*S4], d2 = p4[g4 + 3*S4];
                float4 rr;
                rr.x = (a.x + b2.x) + (c2.x + d2.x);
                rr.y = (a.y + b2.y) + (c2.y + d2.y);
                rr.z = (a.z + b2.z) + (c2.z + d2.z);
                rr.w = (a.w + b2.w) + (c2.w + d2.w);
                o4[g4] = rr;
            }
        }
    }
}

// XCD-chunked bijective swizzle for 512-block grids (512 = 8 XCDs * 64).
__device__ __forceinline__ int xcd_swz512(int id){ return (id & 7) * 64 + (id >> 3); }

// GEMM1 (W1t = Bt1 * Ag1^T, 4096x1024) and GEMM3 (W2t = Bg2t * Ag2^T,
// 1024x4096) fused into one 512-block launch: both K=2048, independent.
__launch_bounds__(256, 2)
__global__ void gemm13_kernel(const unsigned short* __restrict__ A1,
                              const unsigned short* __restrict__ B1,
                              unsigned short* __restrict__ C1,
                              const unsigned short* __restrict__ A2,
                              const unsigned short* __restrict__ B2,
                              unsigned short* __restrict__ C2)
{
    __shared__ unsigned short smem[2 * 16384];   // 64 KB, 2 pipeline slots
    int id = xcd_swz512(blockIdx.x);
    if (id < 256){
        gemm_body<0>(smem, A1, B1, C1, 1024, 2048, 2048, 0,
                     (id >> 3) * 128, (id & 7) * 128);
    } else {
        id -= 256;
        gemm_body<0>(smem, A2, B2, C2, 4096, 2048, 2048, 0,
                     (id >> 5) * 128, (id & 31) * 128);
    }
}

// GEMM2: h(2048x4096) = gelu( x16 * W1t^T ), K=1024
__launch_bounds__(256, 2)
__global__ void gemm2_kernel(const unsigned short* __restrict__ A,
                             const unsigned short* __restrict__ Bt,
                             unsigned short* __restrict__ C)
{
    __shared__ unsigned short smem[2 * 16384];
    int id = xcd_swz512(blockIdx.x);
    gemm_body<1>(smem, A, Bt, C, 4096, 1024, 1024, 0,
                 (id >> 5) * 128, (id & 31) * 128);
}

// GEMM4: out(2048x1024) = hbuf * W2t^T, split-K=4 fp32 partials with fused
// last-arriver reduction (no separate reduce dispatch).
__launch_bounds__(256, 2)
__global__ void gemm4_kernel(const unsigned short* __restrict__ A,
                             const unsigned short* __restrict__ Bt,
                             float* __restrict__ part,
                             float* __restrict__ outp,
                             int* __restrict__ cnt)
{
    __shared__ unsigned short smem[2 * 16384];
    int id = xcd_swz512(blockIdx.x);
    int bz = id >> 7;                  // slice 0..3
    int r  = id & 127;                 // output tile 0..127
    float* Cs = part + (size_t)bz * (2048 * 1024);
    gemm_body<4>(smem, A, Bt, Cs, 1024, 4096, 1024, bz * 1024,
                 (r >> 3) * 128, (r & 7) * 128, part, outp, cnt, r);
}

// ---------------------------------------------------------------------------
extern "C" void kernel_launch(void* const* d_in, const int* in_sizes, int n_in,
                              void* d_out, int out_size, void* d_ws, size_t ws_size,
                              hipStream_t stream)
{
    const float* x    = (const float*)d_in[0];   // (2,1024,1024)
    const float* fc1A = (const float*)d_in[1];   // (256,1024,64)
    const float* fc1B = (const float*)d_in[2];   // (256,64,4096)
    const float* fc2A = (const float*)d_in[3];   // (256,4096,64)
    const float* fc2B = (const float*)d_in[4];   // (256,64,1024)
    const float* lg1  = (const float*)d_in[5];   // (256,)
    const float* lg2  = (const float*)d_in[6];   // (256,)
    float* out = (float*)d_out;                  // (2,1024,1024) fp32

    char* ws = (char*)d_ws;
    int*            idxb = (int*)(ws + 0);                           // 64 ints
    float*          wb   = (float*)(ws + 256);                       // 64 floats
    int*            cnt  = (int*)(ws + 512);                         // 128 tile counters
    char* base = ws + 4096;
    unsigned short* x16  = (unsigned short*)(base);                  // 4 MB  (2048x1024)
    unsigned short* Ag1  = (unsigned short*)(base + (4ull  << 20));  // 4 MB  (1024x2048)
    unsigned short* Bt1  = (unsigned short*)(base + (8ull  << 20));  // 16 MB (4096x2048)
    unsigned short* Ag2  = (unsigned short*)(base + (24ull << 20));  // 16 MB (4096x2048)
    unsigned short* Bg2t = (unsigned short*)(base + (40ull << 20));  // 4 MB  (1024x2048)
    unsigned short* W1t  = (unsigned short*)(base + (44ull << 20));  // 8 MB  (4096x1024)
    unsigned short* W2t  = (unsigned short*)(base + (52ull << 20));  // 8 MB  (1024x4096)
    unsigned short* hbuf = (unsigned short*)(base + (60ull << 20));  // 16 MB (2048x4096)
    float*          part = (float*)(base + (76ull << 20));           // 32 MB (4 x 2048x1024 fp32)

    // 1. top-k + softmax (blocks 0-1) fused with x->bf16 (blocks 2..2049)
    topk_conv_kernel<<<dim3(2050), dim3(256), 0, stream>>>(lg1, lg2, idxb, wb, x, x16);

    // 2. all four gathers (one launch); also resets gemm4 tile counters
    gather_kernel<<<dim3(12800), dim3(256), 0, stream>>>(
        fc1A, Ag1, fc1B, Bt1, fc2A, Ag2, fc2B, Bg2t, idxb, wb, cnt);

    // 3. GEMM1+GEMM3 fused (512 blocks, 2/CU, XCD-swizzled)
    gemm13_kernel<<<dim3(512), dim3(256), 0, stream>>>(Bt1, Ag1, W1t, Bg2t, Ag2, W2t);

    // 4. GEMM2: h = gelu( x16 * W1t^T )
    gemm2_kernel<<<dim3(512), dim3(256), 0, stream>>>(x16, W1t, hbuf);

    // 5. GEMM4: split-K=4 with fused cross-block reduction -> out
    gemm4_kernel<<<dim3(512), dim3(256), 0, stream>>>(hbuf, W2t, part, out, cnt);
}